// Round 20
// baseline (3116.758 us; speedup 1.0000x reference)
//
#include <hip/hip_runtime.h>

typedef unsigned short u16;
typedef __attribute__((ext_vector_type(8))) __bf16 bf16x8;
typedef __attribute__((ext_vector_type(4))) float f32x4;

#define DEV static __device__ __forceinline__

#define ARENA_BYTES 349700096ULL
__device__ __align__(256) char g_arena[ARENA_BYTES];

DEV float bf2f(u16 u) { return __uint_as_float(((unsigned)u) << 16); }
DEV u16 f2bf(float f) {
    unsigned u = __float_as_uint(f);
    return (u16)((u + 0x7fffu + ((u >> 16) & 1u)) >> 16);
}
// tanh-GELU via sigmoid identity + hw exp (proven r17)
DEV float gelu_fast(float x) {
    float x3 = x * x * x;
    float u = 1.5957691216057308f * x + 0.0713548162726009f * x3;
    return x / (1.f + __expf(-u));
}

// ---- async global->LDS, 16B per lane (m97 pattern; lane i -> ldsbase + i*16) ----
DEV void gload16(const u16* gp, u16* lp) {
    __builtin_amdgcn_global_load_lds((const __attribute__((address_space(1))) void*)gp,
                                     (__attribute__((address_space(3))) void*)lp, 16, 0, 0);
}

// ---- target_positions dtype sniff ----
__global__ __launch_bounds__(256) void k_detect_i64(const int* __restrict__ pos, int nhalf,
                                                    int* __restrict__ flagD) {
    int i = blockIdx.x * 256 + threadIdx.x;
    if (i < nhalf && pos[2 * i + 1] != 0) atomicAnd(flagD, 0);
}

// ---- gather rows of spatial_pos_embed -> bf16 ----
__global__ __launch_bounds__(256) void k_gatherB(const float* __restrict__ spe,
                                                 const int* __restrict__ pos,
                                                 const int* __restrict__ flagD,
                                                 u16* __restrict__ qb) {
    int row = blockIdx.x;
    int p = (*flagD) ? pos[2 * row] : pos[row];
    p = (p < 0) ? 0 : (p > 195 ? 195 : p);
    const float* src = spe + (size_t)p * 768;
    size_t o = (size_t)row * 768;
    for (int i = threadIdx.x; i < 768; i += 256) qb[o + i] = f2bf(src[i]);
}

// ---- LayerNorm over 768: fp32 in, bf16 out (OUTF32=0) or fp32 out (final) ----
template <int OUTF32>
__global__ __launch_bounds__(256) void k_ln(const float* __restrict__ X,
                                            const float* __restrict__ g,
                                            const float* __restrict__ b,
                                            u16* __restrict__ Ob, float* __restrict__ Of) {
    const int row = blockIdx.x, tid = threadIdx.x;
    const float* xr = X + (size_t)row * 768;
    float v0 = xr[tid], v1 = xr[tid + 256], v2 = xr[tid + 512];
    float s = v0 + v1 + v2, s2 = v0 * v0 + v1 * v1 + v2 * v2;
#pragma unroll
    for (int off = 32; off; off >>= 1) {
        s += __shfl_xor(s, off);
        s2 += __shfl_xor(s2, off);
    }
    __shared__ float red[8];
    const int wid = tid >> 6, lane = tid & 63;
    if (lane == 0) { red[wid] = s; red[4 + wid] = s2; }
    __syncthreads();
    s = red[0] + red[1] + red[2] + red[3];
    s2 = red[4] + red[5] + red[6] + red[7];
    const float mu = s * (1.f / 768.f);
    const float var = fmaxf(s2 * (1.f / 768.f) - mu * mu, 0.f);
    const float rs = rsqrtf(var + 1e-5f);
    size_t o = (size_t)row * 768;
#pragma unroll
    for (int i = 0; i < 3; ++i) {
        int c = tid + 256 * i;
        float vv = (i == 0 ? v0 : (i == 1 ? v1 : v2));
        float y = (vv - mu) * rs * g[c] + b[c];
        if (OUTF32) Of[o + c] = y;
        else        Ob[o + c] = f2bf(y);
    }
}

// ---- batched weight transpose+convert: L layers, W[l][K,N] -> WT[l][N,K] ----
__global__ __launch_bounds__(256) void k_wtransL(const float* __restrict__ W,
                                                 u16* __restrict__ WT, int K, int N,
                                                 long long srcLs, long long dstLs,
                                                 long long per, int L) {
    long long idx = (long long)blockIdx.x * 256 + threadIdx.x;
    if (idx >= per * L) return;
    int l = (int)(idx / per);
    long long r = idx % per;
    int n = (int)(r % N);
    int kc = (int)(r / N);
    const float* Wl = W + (long long)l * srcLs;
    u16* WTl = WT + (long long)l * dstLs;
    union { u16 u[8]; int4 v; } tmp;
#pragma unroll
    for (int j = 0; j < 8; ++j) tmp.u[j] = f2bf(Wl[(size_t)(kc * 8 + j) * N + n]);
    *(int4*)&WTl[(size_t)n * K + kc * 8] = tmp.v;
}

// ---- bf16 MFMA GEMM (r17-proven, fallback for M%256!=0): 128x128, BK=64, dbuf ----
template <bool GELU_, bool RES_, bool OF32, bool OBF>
__global__ __launch_bounds__(256) void k_gemmB(const u16* __restrict__ A,
                                               const u16* __restrict__ BT,
                                               const float* __restrict__ bias,
                                               const float* __restrict__ R,
                                               float* __restrict__ Cf, u16* __restrict__ Cb,
                                               int M, int N, int K) {
    __shared__ __align__(16) u16 Asm[2][128 * 64];
    __shared__ __align__(16) u16 Bsm[2][128 * 64];
    const int tid = threadIdx.x;
    const int lane = tid & 63;
    const int wid = tid >> 6;
    const int wm = wid >> 1, wn = wid & 1;

    const int nbx = gridDim.x, nby = gridDim.y;
    const int nwg = nbx * nby;
    const int bid = blockIdx.y * nbx + blockIdx.x;
    const int q8 = nwg >> 3, r8 = nwg & 7;
    const int xcd = bid & 7, pos = bid >> 3;
    const int swz = (xcd < r8 ? xcd * (q8 + 1) : r8 * (q8 + 1) + (xcd - r8) * q8) + pos;
    const int tyy = swz % nby;
    const int txx = swz / nby;

    const int srow = lane >> 3;
    const int sgr = (lane & 7) ^ srow;
    const int fr = lane & 15, g = lane >> 4;
    const int s7 = fr & 7;

    const u16* Ab = A + (size_t)txx * 128 * K + (size_t)srow * K + sgr * 8;
    const u16* Bb = BT + (size_t)tyy * 128 * K + (size_t)srow * K + sgr * 8;

    f32x4 acc[4][4] = {};
    const int nIter = K >> 6;

#pragma unroll
    for (int n = 0; n < 4; ++n) {
        const int rg = wid * 32 + n * 8;
        gload16(Ab + (size_t)rg * K, &Asm[0][rg * 64]);
        gload16(Bb + (size_t)rg * K, &Bsm[0][rg * 64]);
    }
    __syncthreads();

    int cur = 0;
    for (int t = 0; t < nIter; ++t) {
        if (t + 1 < nIter) {
            const int k0 = (t + 1) << 6;
#pragma unroll
            for (int n = 0; n < 4; ++n) {
                const int rg = wid * 32 + n * 8;
                gload16(Ab + (size_t)rg * K + k0, &Asm[cur ^ 1][rg * 64]);
                gload16(Bb + (size_t)rg * K + k0, &Bsm[cur ^ 1][rg * 64]);
            }
        }
        const u16* As = &Asm[cur][0];
        const u16* Bs = &Bsm[cur][0];
#pragma unroll
        for (int kk = 0; kk < 2; ++kk) {
            const int gr8 = (((kk * 4 + g) ^ s7) << 3);
            bf16x8 af[4], bfr[4];
#pragma unroll
            for (int i = 0; i < 4; ++i)
                af[i] = *(const bf16x8*)&As[(wm * 64 + i * 16 + fr) * 64 + gr8];
#pragma unroll
            for (int j = 0; j < 4; ++j)
                bfr[j] = *(const bf16x8*)&Bs[(wn * 64 + j * 16 + fr) * 64 + gr8];
#pragma unroll
            for (int i = 0; i < 4; ++i)
#pragma unroll
                for (int j = 0; j < 4; ++j)
                    acc[i][j] = __builtin_amdgcn_mfma_f32_16x16x32_bf16(af[i], bfr[j], acc[i][j], 0, 0, 0);
        }
        __syncthreads();
        cur ^= 1;
    }

    const int g4 = (lane >> 4) * 4;
#pragma unroll
    for (int j = 0; j < 4; ++j) {
        const int col = tyy * 128 + wn * 64 + j * 16 + fr;
        const float bc = bias[col];
#pragma unroll
        for (int i = 0; i < 4; ++i) {
#pragma unroll
            for (int r = 0; r < 4; ++r) {
                const int row = txx * 128 + wm * 64 + i * 16 + g4 + r;
                float v = acc[i][j][r] + bc;
                if (GELU_) v = gelu_fast(v);
                if (RES_)  v += R[(size_t)row * N + col];
                if (OF32)  Cf[(size_t)row * N + col] = v;
                if (OBF)   Cb[(size_t)row * N + col] = f2bf(v);
            }
        }
    }
}

// ---- bf16 MFMA GEMM v6 "P": 256x128 tile, 8 waves (4Mx2N), BK=64,
//      3-stage circular LDS (144KB) + counted vmcnt, ONE barrier per K-step.
//      Invariant at barrier of iter t: every wave has (a) retired its reads of
//      buf[t%3] (lgkmcnt 0) and (b) confirmed its own stage(t+1) loads landed
//      (vmcnt 6 = exactly stage(t+2)'s outstanding). Post-barrier: buf[(t+1)%3]
//      globally valid; buf[t%3] safe to overwrite with stage(t+3).
//      Staging/read swizzle and MFMA order bit-identical to k_gemmB. ----
template <bool GELU_, bool RES_, bool OF32, bool OBF>
__global__ __launch_bounds__(512) void k_gemmP(const u16* __restrict__ A,
                                               const u16* __restrict__ BT,
                                               const float* __restrict__ bias,
                                               const float* __restrict__ R,
                                               float* __restrict__ Cf, u16* __restrict__ Cb,
                                               int M, int N, int K) {
    __shared__ __align__(16) u16 Asm[3][256 * 64];
    __shared__ __align__(16) u16 Bsm[3][128 * 64];
    const int tid = threadIdx.x;
    const int lane = tid & 63;
    const int wid = tid >> 6;          // 0..7
    const int wm = wid >> 1;           // 0..3 (M)
    const int wn = wid & 1;            // 0..1 (N)

    const int nbx = gridDim.x, nby = gridDim.y;
    const int nwg = nbx * nby;
    const int bid = blockIdx.y * nbx + blockIdx.x;
    const int q8 = nwg >> 3, r8 = nwg & 7;
    const int xcd = bid & 7, pos = bid >> 3;
    const int swz = (xcd < r8 ? xcd * (q8 + 1) : r8 * (q8 + 1) + (xcd - r8) * q8) + pos;
    const int tyy = swz % nby;
    const int txx = swz / nby;

    const int srow = lane >> 3;
    const int sgr = (lane & 7) ^ srow;       // XOR-swizzled source granule (bit-exact r14)
    const int fr = lane & 15, g = lane >> 4;
    const int s7 = fr & 7;

    const u16* Ab = A + (size_t)txx * 256 * K + (size_t)srow * K + sgr * 8;
    const u16* Bb = BT + (size_t)tyy * 128 * K + (size_t)srow * K + sgr * 8;

    f32x4 acc[4][4] = {};
    const int nIter = K >> 6;

    // stage(t -> buf): 6 gload16 per wave (A: 32 rows, B: 16 rows)
    auto stage = [&](int t, int buf) {
        const int k0 = t << 6;
#pragma unroll
        for (int n = 0; n < 4; ++n) {
            const int rg = wid * 32 + n * 8;
            gload16(Ab + (size_t)rg * K + k0, &Asm[buf][rg * 64]);
        }
#pragma unroll
        for (int n = 0; n < 2; ++n) {
            const int rg = wid * 16 + n * 8;
            gload16(Bb + (size_t)rg * K + k0, &Bsm[buf][rg * 64]);
        }
    };

    // prologue: fill 3 stages, wait for stage 0 only (counted)
    const int npro = (nIter < 3) ? nIter : 3;
    for (int s = 0; s < npro; ++s) stage(s, s);
    if (npro == 3)      asm volatile("s_waitcnt vmcnt(12)" ::: "memory");
    else if (npro == 2) asm volatile("s_waitcnt vmcnt(6)" ::: "memory");
    else                asm volatile("s_waitcnt vmcnt(0)" ::: "memory");
    __builtin_amdgcn_s_barrier();

    for (int t = 0; t < nIter; ++t) {
        const u16* As = &Asm[t % 3][0];
        const u16* Bs = &Bsm[t % 3][0];
#pragma unroll
        for (int kk = 0; kk < 2; ++kk) {
            const int gr8 = (((kk * 4 + g) ^ s7) << 3);
            bf16x8 af[4], bfr[4];
#pragma unroll
            for (int i = 0; i < 4; ++i)
                af[i] = *(const bf16x8*)&As[(wm * 64 + i * 16 + fr) * 64 + gr8];
#pragma unroll
            for (int j = 0; j < 4; ++j)
                bfr[j] = *(const bf16x8*)&Bs[(wn * 64 + j * 16 + fr) * 64 + gr8];
#pragma unroll
            for (int i = 0; i < 4; ++i)
#pragma unroll
                for (int j = 0; j < 4; ++j)
                    acc[i][j] = __builtin_amdgcn_mfma_f32_16x16x32_bf16(af[i], bfr[j], acc[i][j], 0, 0, 0);
        }
        if (t + 1 < nIter) {
            asm volatile("s_waitcnt lgkmcnt(0)" ::: "memory");
            if (t + 2 < nIter) asm volatile("s_waitcnt vmcnt(6)" ::: "memory");
            else               asm volatile("s_waitcnt vmcnt(0)" ::: "memory");
            __builtin_amdgcn_s_barrier();
            if (t + 3 < nIter) stage(t + 3, t % 3);
        }
    }

    // C/D layout: col=lane&15, row=(lane>>4)*4+reg  [HW-verified m89/m91]
    const int g4 = (lane >> 4) * 4;
#pragma unroll
    for (int j = 0; j < 4; ++j) {
        const int col = tyy * 128 + wn * 64 + j * 16 + fr;
        const float bc = bias[col];
#pragma unroll
        for (int i = 0; i < 4; ++i) {
#pragma unroll
            for (int r = 0; r < 4; ++r) {
                const int row = txx * 256 + wm * 64 + i * 16 + g4 + r;
                float v = acc[i][j][r] + bc;
                if (GELU_) v = gelu_fast(v);
                if (RES_)  v += R[(size_t)row * N + col];
                if (OF32)  Cf[(size_t)row * N + col] = v;
                if (OBF)   Cb[(size_t)row * N + col] = f2bf(v);
            }
        }
    }
}

// ---- MFMA flash attention, bf16 in / bf16 out (structure proven r11-r19) ----
__global__ __launch_bounds__(256) void k_attnM(const u16* __restrict__ Qp, int qs,
                                               const u16* __restrict__ Kp, int ks,
                                               const u16* __restrict__ Vp, int vs,
                                               u16* __restrict__ Op, int os,
                                               int Tq, int Tk) {
    __shared__ u16 kl[208][72];
    __shared__ u16 vt[64][272];
    __shared__ u16 pl[4][16][72];
    const int bh = blockIdx.x, b = bh / 12, h = bh % 12;
    const int tid = threadIdx.x, lane = tid & 63, wid = tid >> 6;
    const int fr = lane & 15, g = lane >> 4, g4 = g * 4;

    const int Tkp = (Tk + 15) & ~15;
    const int NC = (Tkp + 63) >> 6;
    const int TC = NC << 6;

    for (int r = wid; r < Tkp; r += 4) {
        kl[r][lane] = (r < Tk) ? Kp[((size_t)b * Tk + r) * ks + h * 64 + lane] : (u16)0;
    }
    for (int t = wid; t < TC; t += 4) {
        vt[lane][t] = (t < Tk) ? Vp[((size_t)b * Tk + t) * vs + h * 64 + lane] : (u16)0;
    }
    __syncthreads();

    const int NT = (Tq + 63) >> 6;
    for (int it = 0; it < NT; ++it) {
        const int qb = (it << 6) + (wid << 4);
        if (qb >= Tq) continue;

        int qr = qb + fr;
        if (qr >= Tq) qr = 0;
        const u16* Qrow = Qp + ((size_t)b * Tq + qr) * qs + h * 64;
        bf16x8 afq0 = *(const bf16x8*)&Qrow[g * 8];
        bf16x8 afq1 = *(const bf16x8*)&Qrow[32 + g * 8];

        f32x4 acc_o[4] = {};
        float m_r[4] = {-1e30f, -1e30f, -1e30f, -1e30f};
        float lp[4] = {0.f, 0.f, 0.f, 0.f};

        for (int c = 0; c < NC; ++c) {
            const int tk0 = c << 6;
            int NF = (Tkp - tk0) >> 4;
            if (NF > 4) NF = 4;

            f32x4 acc_s[4] = {};
#pragma unroll
            for (int nf = 0; nf < 4; ++nf) {
                if (nf < NF) {
                    const u16* kr = &kl[tk0 + nf * 16 + fr][0];
                    acc_s[nf] = __builtin_amdgcn_mfma_f32_16x16x32_bf16(
                        afq0, *(const bf16x8*)&kr[g * 8], acc_s[nf], 0, 0, 0);
                    acc_s[nf] = __builtin_amdgcn_mfma_f32_16x16x32_bf16(
                        afq1, *(const bf16x8*)&kr[32 + g * 8], acc_s[nf], 0, 0, 0);
                }
            }
            float pm[4] = {-1e30f, -1e30f, -1e30f, -1e30f};
#pragma unroll
            for (int nf = 0; nf < 4; ++nf) {
                if (nf < NF) {
                    const bool cv = (tk0 + nf * 16 + fr) < Tk;
#pragma unroll
                    for (int r = 0; r < 4; ++r) {
                        float sv = acc_s[nf][r] * 0.125f;
                        acc_s[nf][r] = sv;
                        if (cv) pm[r] = fmaxf(pm[r], sv);
                    }
                }
            }
#pragma unroll
            for (int off = 1; off < 16; off <<= 1)
#pragma unroll
                for (int r = 0; r < 4; ++r) pm[r] = fmaxf(pm[r], __shfl_xor(pm[r], off));
            float al[4];
#pragma unroll
            for (int r = 0; r < 4; ++r) {
                float mn = fmaxf(m_r[r], pm[r]);
                al[r] = __expf(m_r[r] - mn);
                m_r[r] = mn;
                lp[r] *= al[r];
            }
#pragma unroll
            for (int nfd = 0; nfd < 4; ++nfd)
#pragma unroll
                for (int r = 0; r < 4; ++r) acc_o[nfd][r] *= al[r];
#pragma unroll
            for (int nf = 0; nf < 4; ++nf) {
                const bool cv = (nf < NF) && ((tk0 + nf * 16 + fr) < Tk);
#pragma unroll
                for (int r = 0; r < 4; ++r) {
                    float w = cv ? __expf(acc_s[nf][r] - m_r[r]) : 0.f;
                    lp[r] += w;
                    pl[wid][g4 + r][nf * 16 + fr] = f2bf(w);
                }
            }
#pragma unroll
            for (int ksp = 0; ksp < 2; ++ksp) {
                bf16x8 ap = *(const bf16x8*)&pl[wid][fr][ksp * 32 + g * 8];
#pragma unroll
                for (int nfd = 0; nfd < 4; ++nfd)
                    acc_o[nfd] = __builtin_amdgcn_mfma_f32_16x16x32_bf16(
                        ap, *(const bf16x8*)&vt[nfd * 16 + fr][tk0 + ksp * 32 + g * 8],
                        acc_o[nfd], 0, 0, 0);
            }
        }
#pragma unroll
        for (int off = 1; off < 16; off <<= 1)
#pragma unroll
            for (int r = 0; r < 4; ++r) lp[r] += __shfl_xor(lp[r], off);
#pragma unroll
        for (int r = 0; r < 4; ++r) {
            int qrow = qb + g4 + r;
            if (qrow < Tq) {
                float inv = 1.f / lp[r];
#pragma unroll
                for (int nfd = 0; nfd < 4; ++nfd)
                    Op[((size_t)b * Tq + qrow) * os + h * 64 + nfd * 16 + fr] =
                        f2bf(acc_o[nfd][r] * inv);
            }
        }
    }
}

// =======================================================================================
extern "C" void kernel_launch(void* const* d_in, const int* in_sizes, int n_in,
                              void* d_out, int out_size, void* d_ws, size_t ws_size,
                              hipStream_t stream) {
    const int D = 768, FF = 3072, NB = 64, S = 196, T = 98, NL = 3;
    const int Menc = NB * S;   // 12544
    const int Mdec = NB * T;   // 6272

    auto IN = [&](int i) { return (const float*)d_in[i]; };
    const int* tpos = (const int*)d_in[1];
    const float* spe = IN(2);
    const float* norm_g = IN(3);
    const float* norm_b = IN(4);

    char* base;
    if (ws_size >= ARENA_BYTES) {
        base = (char*)d_ws;
    } else {
        void* sym = nullptr;
        if (hipGetSymbolAddress(&sym, HIP_SYMBOL(g_arena)) == hipSuccess && sym)
            base = (char*)sym;
        else
            base = (char*)d_ws;
    }
    char* pp = base;
    auto alloc = [&](long long bytes) -> void* {
        void* r = (void*)pp;
        pp += (bytes + 255) & ~255LL;
        return r;
    };
    int* flag = (int*)alloc(256);
    int* flagD = flag + 1;

    // ---- batched weight pre-conversion: W[L][K,N] fp32 -> WT[L][N,K] bf16 ----
    auto cvb = [&](const float* W, int K, int N, int L, long long dstLs, u16* dst) {
        long long per = (long long)N * (K / 8);
        long long tot = per * L;
        k_wtransL<<<dim3((int)((tot + 255) / 256)), dim3(256), 0, stream>>>(
            W, dst, K, N, (long long)K * N, dstLs, per, L);
    };
    auto cva = [&](const float* W, int K, int N, int L) -> u16* {
        u16* dst = (u16*)alloc((long long)L * K * N * 2);
        cvb(W, K, N, L, (long long)K * N, dst);
        return dst;
    };
    u16* encWqkv = cva(IN(7), D, 3 * D, 3);
    u16* encWo = cva(IN(9), D, D, 3);
    u16* encW1 = cva(IN(13), D, FF, 3);
    u16* encW2 = cva(IN(15), FF, D, 3);
    u16* decWqkv = cva(IN(19), D, 3 * D, 3);
    u16* decWo = cva(IN(21), D, D, 3);
    u16* decW1 = cva(IN(25), D, FF, 3);
    u16* decW2 = cva(IN(27), FF, D, 3);
    u16* caWq = cva(IN(29), D, D, 3);
    u16* caWkv = (u16*)alloc((long long)3 * 2 * D * D * 2);   // [l][wk rows | wv rows][768]
    cvb(IN(31), D, D, 3, (long long)2 * D * D, caWkv);
    cvb(IN(33), D, D, 3, (long long)2 * D * D, caWkv + (long long)D * D);
    u16* caWo = cva(IN(35), D, D, 3);
    float* bkv[3];
    for (int l = 0; l < NL; ++l) {
        bkv[l] = (float*)alloc(2 * D * 4);
        hipMemcpyAsync(bkv[l], IN(32) + l * D, D * 4, hipMemcpyDeviceToDevice, stream);
        hipMemcpyAsync(bkv[l] + D, IN(34) + l * D, D * 4, hipMemcpyDeviceToDevice, stream);
    }

    float* x = (float*)alloc((long long)Menc * D * 4);   // fp32 residual (enc)
    float* q = (float*)alloc((long long)Mdec * D * 4);   // fp32 residual (dec)
    u16* xb = (u16*)alloc((long long)Menc * D * 2);      // bf16 mirror of x
    u16* qb = (u16*)alloc((long long)Mdec * D * 2);      // bf16 mirror of q
    u16* hb = (u16*)alloc((long long)Menc * D * 2);      // bf16 LN/attn out
    u16* s1b = (u16*)alloc((long long)Menc * FF * 2);    // bf16 qkv / ff1 / dec qq,kkvv

    hipMemsetAsync(flagD, 0x01, 4, stream);
    k_detect_i64<<<dim3((Mdec / 2 + 255) / 256), dim3(256), 0, stream>>>(tpos, Mdec / 2, flagD);

    // modes: 0 plain->bf16 | 1 res->fp32+bf16 | 2 gelu->bf16 | 3 plain->fp32+bf16
    auto gemm = [&](int mode, const u16* A, const u16* WT, const float* bias,
                    const float* R, float* Cf, u16* Cb, int M, int N, int K) {
        if (M % 256 == 0) {
            dim3 g(M / 256, N / 128), blk(512);
            switch (mode) {
                case 0: k_gemmP<false, false, false, true><<<g, blk, 0, stream>>>(A, WT, bias, nullptr, nullptr, Cb, M, N, K); break;
                case 1: k_gemmP<false, true, true, true><<<g, blk, 0, stream>>>(A, WT, bias, R, Cf, Cb, M, N, K); break;
                case 2: k_gemmP<true, false, false, true><<<g, blk, 0, stream>>>(A, WT, bias, nullptr, nullptr, Cb, M, N, K); break;
                case 3: k_gemmP<false, false, true, true><<<g, blk, 0, stream>>>(A, WT, bias, nullptr, Cf, Cb, M, N, K); break;
            }
        } else {
            dim3 g(M / 128, N / 128), blk(256);
            switch (mode) {
                case 0: k_gemmB<false, false, false, true><<<g, blk, 0, stream>>>(A, WT, bias, nullptr, nullptr, Cb, M, N, K); break;
                case 1: k_gemmB<false, true, true, true><<<g, blk, 0, stream>>>(A, WT, bias, R, Cf, Cb, M, N, K); break;
                case 2: k_gemmB<true, false, false, true><<<g, blk, 0, stream>>>(A, WT, bias, nullptr, nullptr, Cb, M, N, K); break;
                case 3: k_gemmB<false, false, true, true><<<g, blk, 0, stream>>>(A, WT, bias, nullptr, Cf, Cb, M, N, K); break;
            }
        }
    };
    auto ln = [&](const float* X, const float* gg, const float* bb, u16* Ob, float* Of, int M) {
        if (Ob) k_ln<0><<<dim3(M), dim3(256), 0, stream>>>(X, gg, bb, Ob, nullptr);
        else    k_ln<1><<<dim3(M), dim3(256), 0, stream>>>(X, gg, bb, nullptr, Of);
    };
    auto attn = [&](const u16* Q, int qs, const u16* Kp, int ks2, const u16* Vp, int vs,
                    u16* O, int Tq, int Tk) {
        k_attnM<<<dim3(NB * 12), dim3(256), 0, stream>>>(Q, qs, Kp, ks2, Vp, vs, O, D, Tq, Tk);
    };

    // pre-norm transformer block; Xf fp32 residual, Xb its bf16 mirror
    auto tblock = [&](float* Xf, u16* Xb, int Mtok, int Tseq, int basei, int l,
                      const u16* Wqkv, const u16* Wo, const u16* W1, const u16* W2) {
        const float* ln1g = IN(basei + 0) + l * D;
        const float* ln1b = IN(basei + 1) + l * D;
        const float* bqkv = IN(basei + 3) + l * 3 * D;
        const float* bo = IN(basei + 5) + l * D;
        const float* ln2g = IN(basei + 6) + l * D;
        const float* ln2b = IN(basei + 7) + l * D;
        const float* b1 = IN(basei + 9) + l * FF;
        const float* b2 = IN(basei + 11) + l * D;

        ln(Xf, ln1g, ln1b, hb, nullptr, Mtok);
        gemm(0, hb, Wqkv, bqkv, nullptr, nullptr, s1b, Mtok, 3 * D, D);         // qkv -> bf16
        attn(s1b, 3 * D, s1b + D, 3 * D, s1b + 2 * D, 3 * D, hb, Tseq, Tseq);   // self-attn -> hb
        gemm(1, hb, Wo, bo, Xf, Xf, Xb, Mtok, D, D);                            // x += ao@wo+bo
        ln(Xf, ln2g, ln2b, hb, nullptr, Mtok);
        gemm(2, hb, W1, b1, nullptr, nullptr, s1b, Mtok, FF, D);                // gelu -> bf16
        gemm(1, s1b, W2, b2, Xf, Xf, Xb, Mtok, D, FF);                          // x += ff@w2+b2
    };

    // ---------------- encoder ----------------
    hipMemcpyAsync(x, IN(0), (long long)Menc * D * 4, hipMemcpyDeviceToDevice, stream);
    for (int l = 0; l < NL; ++l)
        tblock(x, xb, Menc, S, 5, l,
               encWqkv + (long long)l * D * 3 * D, encWo + (long long)l * D * D,
               encW1 + (long long)l * D * FF, encW2 + (long long)l * FF * D);

    // ---------------- decoder ----------------
    k_gatherB<<<dim3(Mdec), dim3(256), 0, stream>>>(spe, tpos, flagD, qb);
    u16* qq = s1b;                                       // [Mdec, D]
    u16* kkvv = s1b + (long long)Mdec * D;               // [Menc, 1536] (kk | vv)
    for (int l = 0; l < NL; ++l) {
        gemm(0, qb, caWq + (long long)l * D * D, IN(30) + l * D, nullptr, nullptr, qq, Mdec, D, D);
        gemm(0, xb, caWkv + (long long)l * 2 * D * D, bkv[l], nullptr, nullptr, kkvv, Menc, 2 * D, D);
        attn(qq, D, kkvv, 2 * D, kkvv + D, 2 * D, hb, T, S);                    // cross-attn
        gemm(3, hb, caWo + (long long)l * D * D, IN(36) + l * D, nullptr, q, qb, Mdec, D, D);
        tblock(q, qb, Mdec, T, 17, l,
               decWqkv + (long long)l * D * 3 * D, decWo + (long long)l * D * D,
               decW1 + (long long)l * D * FF, decW2 + (long long)l * FF * D);
    }
    ln(q, norm_g, norm_b, nullptr, (float*)d_out, Mdec);
}

// Round 21
// 2895.436 us; speedup vs baseline: 1.0764x; 1.0764x over previous
//
#include <hip/hip_runtime.h>

typedef unsigned short u16;
typedef __attribute__((ext_vector_type(8))) __bf16 bf16x8;
typedef __attribute__((ext_vector_type(4))) float f32x4;

#define DEV static __device__ __forceinline__

#define ARENA_BYTES 349700096ULL
__device__ __align__(256) char g_arena[ARENA_BYTES];

DEV float bf2f(u16 u) { return __uint_as_float(((unsigned)u) << 16); }
DEV u16 f2bf(float f) {
    unsigned u = __float_as_uint(f);
    return (u16)((u + 0x7fffu + ((u >> 16) & 1u)) >> 16);
}
// tanh-GELU via sigmoid identity + hw exp (proven r17)
DEV float gelu_fast(float x) {
    float x3 = x * x * x;
    float u = 1.5957691216057308f * x + 0.0713548162726009f * x3;
    return x / (1.f + __expf(-u));
}

// ---- async global->LDS, 16B per lane (m97 pattern; lane i -> ldsbase + i*16) ----
DEV void gload16(const u16* gp, u16* lp) {
    __builtin_amdgcn_global_load_lds((const __attribute__((address_space(1))) void*)gp,
                                     (__attribute__((address_space(3))) void*)lp, 16, 0, 0);
}

// ---- target_positions dtype sniff ----
__global__ __launch_bounds__(256) void k_detect_i64(const int* __restrict__ pos, int nhalf,
                                                    int* __restrict__ flagD) {
    int i = blockIdx.x * 256 + threadIdx.x;
    if (i < nhalf && pos[2 * i + 1] != 0) atomicAnd(flagD, 0);
}

// ---- gather rows of spatial_pos_embed -> bf16 ----
__global__ __launch_bounds__(256) void k_gatherB(const float* __restrict__ spe,
                                                 const int* __restrict__ pos,
                                                 const int* __restrict__ flagD,
                                                 u16* __restrict__ qb) {
    int row = blockIdx.x;
    int p = (*flagD) ? pos[2 * row] : pos[row];
    p = (p < 0) ? 0 : (p > 195 ? 195 : p);
    const float* src = spe + (size_t)p * 768;
    size_t o = (size_t)row * 768;
    for (int i = threadIdx.x; i < 768; i += 256) qb[o + i] = f2bf(src[i]);
}

// ---- LayerNorm over 768: fp32 in, bf16 out (OUTF32=0) or fp32 out (final) ----
template <int OUTF32>
__global__ __launch_bounds__(256) void k_ln(const float* __restrict__ X,
                                            const float* __restrict__ g,
                                            const float* __restrict__ b,
                                            u16* __restrict__ Ob, float* __restrict__ Of) {
    const int row = blockIdx.x, tid = threadIdx.x;
    const float* xr = X + (size_t)row * 768;
    float v0 = xr[tid], v1 = xr[tid + 256], v2 = xr[tid + 512];
    float s = v0 + v1 + v2, s2 = v0 * v0 + v1 * v1 + v2 * v2;
#pragma unroll
    for (int off = 32; off; off >>= 1) {
        s += __shfl_xor(s, off);
        s2 += __shfl_xor(s2, off);
    }
    __shared__ float red[8];
    const int wid = tid >> 6, lane = tid & 63;
    if (lane == 0) { red[wid] = s; red[4 + wid] = s2; }
    __syncthreads();
    s = red[0] + red[1] + red[2] + red[3];
    s2 = red[4] + red[5] + red[6] + red[7];
    const float mu = s * (1.f / 768.f);
    const float var = fmaxf(s2 * (1.f / 768.f) - mu * mu, 0.f);
    const float rs = rsqrtf(var + 1e-5f);
    size_t o = (size_t)row * 768;
#pragma unroll
    for (int i = 0; i < 3; ++i) {
        int c = tid + 256 * i;
        float vv = (i == 0 ? v0 : (i == 1 ? v1 : v2));
        float y = (vv - mu) * rs * g[c] + b[c];
        if (OUTF32) Of[o + c] = y;
        else        Ob[o + c] = f2bf(y);
    }
}

// ---- batched weight transpose+convert: L layers, W[l][K,N] -> WT[l][N,K] ----
__global__ __launch_bounds__(256) void k_wtransL(const float* __restrict__ W,
                                                 u16* __restrict__ WT, int K, int N,
                                                 long long srcLs, long long dstLs,
                                                 long long per, int L) {
    long long idx = (long long)blockIdx.x * 256 + threadIdx.x;
    if (idx >= per * L) return;
    int l = (int)(idx / per);
    long long r = idx % per;
    int n = (int)(r % N);
    int kc = (int)(r / N);
    const float* Wl = W + (long long)l * srcLs;
    u16* WTl = WT + (long long)l * dstLs;
    union { u16 u[8]; int4 v; } tmp;
#pragma unroll
    for (int j = 0; j < 8; ++j) tmp.u[j] = f2bf(Wl[(size_t)(kc * 8 + j) * N + n]);
    *(int4*)&WTl[(size_t)n * K + kc * 8] = tmp.v;
}

// ---- bf16 MFMA GEMM (r17-proven): 128x128 tile, BK=64, double-buffered 2-phase
//      prefetch, XOR-swizzled gload_lds staging, bijective XCD block swizzle. ----
template <bool GELU_, bool RES_, bool OF32, bool OBF>
__global__ __launch_bounds__(256) void k_gemmB(const u16* __restrict__ A,
                                               const u16* __restrict__ BT,
                                               const float* __restrict__ bias,
                                               const float* __restrict__ R,
                                               float* __restrict__ Cf, u16* __restrict__ Cb,
                                               int M, int N, int K) {
    __shared__ __align__(16) u16 Asm[2][128 * 64];
    __shared__ __align__(16) u16 Bsm[2][128 * 64];
    const int tid = threadIdx.x;
    const int lane = tid & 63;
    const int wid = tid >> 6;
    const int wm = wid >> 1, wn = wid & 1;

    // XCD-chunked bijective swizzle; N-tile-fastest within a chunk (A-panel L2 reuse)
    const int nbx = gridDim.x, nby = gridDim.y;
    const int nwg = nbx * nby;
    const int bid = blockIdx.y * nbx + blockIdx.x;
    const int q8 = nwg >> 3, r8 = nwg & 7;
    const int xcd = bid & 7, pos = bid >> 3;
    const int swz = (xcd < r8 ? xcd * (q8 + 1) : r8 * (q8 + 1) + (xcd - r8) * q8) + pos;
    const int tyy = swz % nby;     // N-tile
    const int txx = swz / nby;     // M-tile

    // staging: lane covers row (lane>>3) in its 8-row group, phys granule (lane&7);
    // global (logical) granule = (lane&7) ^ (lane>>3)  [XOR swizzle, bit-exact r14]
    const int srow = lane >> 3;
    const int sgr = (lane & 7) ^ srow;
    const int fr = lane & 15, g = lane >> 4;
    const int s7 = fr & 7;          // read-side swizzle selector (= row & 7)

    const u16* Ab = A + (size_t)txx * 128 * K + (size_t)srow * K + sgr * 8;
    const u16* Bb = BT + (size_t)tyy * 128 * K + (size_t)srow * K + sgr * 8;

    f32x4 acc[4][4] = {};
    const int nIter = K >> 6;

    // prologue: stage tile 0 into buffer 0
#pragma unroll
    for (int n = 0; n < 4; ++n) {
        const int rg = wid * 32 + n * 8;
        gload16(Ab + (size_t)rg * K, &Asm[0][rg * 64]);
        gload16(Bb + (size_t)rg * K, &Bsm[0][rg * 64]);
    }
    __syncthreads();

    int cur = 0;
    for (int t = 0; t < nIter; ++t) {
        if (t + 1 < nIter) {
            const int k0 = (t + 1) << 6;
#pragma unroll
            for (int n = 0; n < 4; ++n) {
                const int rg = wid * 32 + n * 8;
                gload16(Ab + (size_t)rg * K + k0, &Asm[cur ^ 1][rg * 64]);
                gload16(Bb + (size_t)rg * K + k0, &Bsm[cur ^ 1][rg * 64]);
            }
        }
        const u16* As = &Asm[cur][0];
        const u16* Bs = &Bsm[cur][0];
#pragma unroll
        for (int kk = 0; kk < 2; ++kk) {
            const int gr8 = (((kk * 4 + g) ^ s7) << 3);
            bf16x8 af[4], bfr[4];
#pragma unroll
            for (int i = 0; i < 4; ++i)
                af[i] = *(const bf16x8*)&As[(wm * 64 + i * 16 + fr) * 64 + gr8];
#pragma unroll
            for (int j = 0; j < 4; ++j)
                bfr[j] = *(const bf16x8*)&Bs[(wn * 64 + j * 16 + fr) * 64 + gr8];
#pragma unroll
            for (int i = 0; i < 4; ++i)
#pragma unroll
                for (int j = 0; j < 4; ++j)
                    acc[i][j] = __builtin_amdgcn_mfma_f32_16x16x32_bf16(af[i], bfr[j], acc[i][j], 0, 0, 0);
        }
        __syncthreads();
        cur ^= 1;
    }

    // C/D layout: col=lane&15, row=(lane>>4)*4+reg  [HW-verified m89/m91]
    const int g4 = (lane >> 4) * 4;
#pragma unroll
    for (int j = 0; j < 4; ++j) {
        const int col = tyy * 128 + wn * 64 + j * 16 + fr;
        const float bc = bias[col];
#pragma unroll
        for (int i = 0; i < 4; ++i) {
#pragma unroll
            for (int r = 0; r < 4; ++r) {
                const int row = txx * 128 + wm * 64 + i * 16 + g4 + r;
                float v = acc[i][j][r] + bc;
                if (GELU_) v = gelu_fast(v);
                if (RES_)  v += R[(size_t)row * N + col];
                if (OF32)  Cf[(size_t)row * N + col] = v;
                if (OBF)   Cb[(size_t)row * N + col] = f2bf(v);
            }
        }
    }
}

// ---- MFMA flash attention, bf16 in / bf16 out (structure proven r11-r19) ----
__global__ __launch_bounds__(256) void k_attnM(const u16* __restrict__ Qp, int qs,
                                               const u16* __restrict__ Kp, int ks,
                                               const u16* __restrict__ Vp, int vs,
                                               u16* __restrict__ Op, int os,
                                               int Tq, int Tk) {
    __shared__ u16 kl[208][72];
    __shared__ u16 vt[64][272];
    __shared__ u16 pl[4][16][72];
    const int bh = blockIdx.x, b = bh / 12, h = bh % 12;
    const int tid = threadIdx.x, lane = tid & 63, wid = tid >> 6;
    const int fr = lane & 15, g = lane >> 4, g4 = g * 4;

    const int Tkp = (Tk + 15) & ~15;
    const int NC = (Tkp + 63) >> 6;
    const int TC = NC << 6;

    for (int r = wid; r < Tkp; r += 4) {
        kl[r][lane] = (r < Tk) ? Kp[((size_t)b * Tk + r) * ks + h * 64 + lane] : (u16)0;
    }
    for (int t = wid; t < TC; t += 4) {
        vt[lane][t] = (t < Tk) ? Vp[((size_t)b * Tk + t) * vs + h * 64 + lane] : (u16)0;
    }
    __syncthreads();

    const int NT = (Tq + 63) >> 6;
    for (int it = 0; it < NT; ++it) {
        const int qb = (it << 6) + (wid << 4);
        if (qb >= Tq) continue;

        int qr = qb + fr;
        if (qr >= Tq) qr = 0;
        const u16* Qrow = Qp + ((size_t)b * Tq + qr) * qs + h * 64;
        bf16x8 afq0 = *(const bf16x8*)&Qrow[g * 8];
        bf16x8 afq1 = *(const bf16x8*)&Qrow[32 + g * 8];

        f32x4 acc_o[4] = {};
        float m_r[4] = {-1e30f, -1e30f, -1e30f, -1e30f};
        float lp[4] = {0.f, 0.f, 0.f, 0.f};

        for (int c = 0; c < NC; ++c) {
            const int tk0 = c << 6;
            int NF = (Tkp - tk0) >> 4;
            if (NF > 4) NF = 4;

            f32x4 acc_s[4] = {};
#pragma unroll
            for (int nf = 0; nf < 4; ++nf) {
                if (nf < NF) {
                    const u16* kr = &kl[tk0 + nf * 16 + fr][0];
                    acc_s[nf] = __builtin_amdgcn_mfma_f32_16x16x32_bf16(
                        afq0, *(const bf16x8*)&kr[g * 8], acc_s[nf], 0, 0, 0);
                    acc_s[nf] = __builtin_amdgcn_mfma_f32_16x16x32_bf16(
                        afq1, *(const bf16x8*)&kr[32 + g * 8], acc_s[nf], 0, 0, 0);
                }
            }
            float pm[4] = {-1e30f, -1e30f, -1e30f, -1e30f};
#pragma unroll
            for (int nf = 0; nf < 4; ++nf) {
                if (nf < NF) {
                    const bool cv = (tk0 + nf * 16 + fr) < Tk;
#pragma unroll
                    for (int r = 0; r < 4; ++r) {
                        float sv = acc_s[nf][r] * 0.125f;
                        acc_s[nf][r] = sv;
                        if (cv) pm[r] = fmaxf(pm[r], sv);
                    }
                }
            }
#pragma unroll
            for (int off = 1; off < 16; off <<= 1)
#pragma unroll
                for (int r = 0; r < 4; ++r) pm[r] = fmaxf(pm[r], __shfl_xor(pm[r], off));
            float al[4];
#pragma unroll
            for (int r = 0; r < 4; ++r) {
                float mn = fmaxf(m_r[r], pm[r]);
                al[r] = __expf(m_r[r] - mn);
                m_r[r] = mn;
                lp[r] *= al[r];
            }
#pragma unroll
            for (int nfd = 0; nfd < 4; ++nfd)
#pragma unroll
                for (int r = 0; r < 4; ++r) acc_o[nfd][r] *= al[r];
#pragma unroll
            for (int nf = 0; nf < 4; ++nf) {
                const bool cv = (nf < NF) && ((tk0 + nf * 16 + fr) < Tk);
#pragma unroll
                for (int r = 0; r < 4; ++r) {
                    float w = cv ? __expf(acc_s[nf][r] - m_r[r]) : 0.f;
                    lp[r] += w;
                    pl[wid][g4 + r][nf * 16 + fr] = f2bf(w);
                }
            }
#pragma unroll
            for (int ksp = 0; ksp < 2; ++ksp) {
                bf16x8 ap = *(const bf16x8*)&pl[wid][fr][ksp * 32 + g * 8];
#pragma unroll
                for (int nfd = 0; nfd < 4; ++nfd)
                    acc_o[nfd] = __builtin_amdgcn_mfma_f32_16x16x32_bf16(
                        ap, *(const bf16x8*)&vt[nfd * 16 + fr][tk0 + ksp * 32 + g * 8],
                        acc_o[nfd], 0, 0, 0);
            }
        }
#pragma unroll
        for (int off = 1; off < 16; off <<= 1)
#pragma unroll
            for (int r = 0; r < 4; ++r) lp[r] += __shfl_xor(lp[r], off);
#pragma unroll
        for (int r = 0; r < 4; ++r) {
            int qrow = qb + g4 + r;
            if (qrow < Tq) {
                float inv = 1.f / lp[r];
#pragma unroll
                for (int nfd = 0; nfd < 4; ++nfd)
                    Op[((size_t)b * Tq + qrow) * os + h * 64 + nfd * 16 + fr] =
                        f2bf(acc_o[nfd][r] * inv);
            }
        }
    }
}

// =======================================================================================
extern "C" void kernel_launch(void* const* d_in, const int* in_sizes, int n_in,
                              void* d_out, int out_size, void* d_ws, size_t ws_size,
                              hipStream_t stream) {
    const int D = 768, FF = 3072, NB = 64, S = 196, T = 98, NL = 3;
    const int Menc = NB * S;   // 12544
    const int Mdec = NB * T;   // 6272

    auto IN = [&](int i) { return (const float*)d_in[i]; };
    const int* tpos = (const int*)d_in[1];
    const float* spe = IN(2);
    const float* norm_g = IN(3);
    const float* norm_b = IN(4);

    char* base;
    if (ws_size >= ARENA_BYTES) {
        base = (char*)d_ws;
    } else {
        void* sym = nullptr;
        if (hipGetSymbolAddress(&sym, HIP_SYMBOL(g_arena)) == hipSuccess && sym)
            base = (char*)sym;
        else
            base = (char*)d_ws;
    }
    char* pp = base;
    auto alloc = [&](long long bytes) -> void* {
        void* r = (void*)pp;
        pp += (bytes + 255) & ~255LL;
        return r;
    };
    int* flag = (int*)alloc(256);
    int* flagD = flag + 1;

    // ---- batched weight pre-conversion: W[L][K,N] fp32 -> WT[L][N,K] bf16 ----
    auto cvb = [&](const float* W, int K, int N, int L, long long dstLs, u16* dst) {
        long long per = (long long)N * (K / 8);
        long long tot = per * L;
        k_wtransL<<<dim3((int)((tot + 255) / 256)), dim3(256), 0, stream>>>(
            W, dst, K, N, (long long)K * N, dstLs, per, L);
    };
    auto cva = [&](const float* W, int K, int N, int L) -> u16* {
        u16* dst = (u16*)alloc((long long)L * K * N * 2);
        cvb(W, K, N, L, (long long)K * N, dst);
        return dst;
    };
    u16* encWqkv = cva(IN(7), D, 3 * D, 3);
    u16* encWo = cva(IN(9), D, D, 3);
    u16* encW1 = cva(IN(13), D, FF, 3);
    u16* encW2 = cva(IN(15), FF, D, 3);
    u16* decWqkv = cva(IN(19), D, 3 * D, 3);
    u16* decWo = cva(IN(21), D, D, 3);
    u16* decW1 = cva(IN(25), D, FF, 3);
    u16* decW2 = cva(IN(27), FF, D, 3);
    u16* caWq = cva(IN(29), D, D, 3);
    u16* caWkv = (u16*)alloc((long long)3 * 2 * D * D * 2);   // [l][wk rows | wv rows][768]
    cvb(IN(31), D, D, 3, (long long)2 * D * D, caWkv);
    cvb(IN(33), D, D, 3, (long long)2 * D * D, caWkv + (long long)D * D);
    u16* caWo = cva(IN(35), D, D, 3);
    float* bkv[3];
    for (int l = 0; l < NL; ++l) {
        bkv[l] = (float*)alloc(2 * D * 4);
        hipMemcpyAsync(bkv[l], IN(32) + l * D, D * 4, hipMemcpyDeviceToDevice, stream);
        hipMemcpyAsync(bkv[l] + D, IN(34) + l * D, D * 4, hipMemcpyDeviceToDevice, stream);
    }

    float* x = (float*)alloc((long long)Menc * D * 4);   // fp32 residual (enc)
    float* q = (float*)alloc((long long)Mdec * D * 4);   // fp32 residual (dec)
    u16* xb = (u16*)alloc((long long)Menc * D * 2);      // bf16 mirror of x
    u16* qb = (u16*)alloc((long long)Mdec * D * 2);      // bf16 mirror of q
    u16* hb = (u16*)alloc((long long)Menc * D * 2);      // bf16 LN/attn out
    u16* s1b = (u16*)alloc((long long)Menc * FF * 2);    // bf16 qkv / ff1 / dec qq,kkvv

    hipMemsetAsync(flagD, 0x01, 4, stream);
    k_detect_i64<<<dim3((Mdec / 2 + 255) / 256), dim3(256), 0, stream>>>(tpos, Mdec / 2, flagD);

    // modes: 0 plain->bf16 | 1 res->fp32+bf16 | 2 gelu->bf16 | 3 plain->fp32+bf16
    auto gemm = [&](int mode, const u16* A, const u16* WT, const float* bias,
                    const float* R, float* Cf, u16* Cb, int M, int N, int K) {
        dim3 g(M / 128, N / 128), blk(256);
        switch (mode) {
            case 0: k_gemmB<false, false, false, true><<<g, blk, 0, stream>>>(A, WT, bias, nullptr, nullptr, Cb, M, N, K); break;
            case 1: k_gemmB<false, true, true, true><<<g, blk, 0, stream>>>(A, WT, bias, R, Cf, Cb, M, N, K); break;
            case 2: k_gemmB<true, false, false, true><<<g, blk, 0, stream>>>(A, WT, bias, nullptr, nullptr, Cb, M, N, K); break;
            case 3: k_gemmB<false, false, true, true><<<g, blk, 0, stream>>>(A, WT, bias, nullptr, Cf, Cb, M, N, K); break;
        }
    };
    auto ln = [&](const float* X, const float* gg, const float* bb, u16* Ob, float* Of, int M) {
        if (Ob) k_ln<0><<<dim3(M), dim3(256), 0, stream>>>(X, gg, bb, Ob, nullptr);
        else    k_ln<1><<<dim3(M), dim3(256), 0, stream>>>(X, gg, bb, nullptr, Of);
    };
    auto attn = [&](const u16* Q, int qs, const u16* Kp, int ks2, const u16* Vp, int vs,
                    u16* O, int Tq, int Tk) {
        k_attnM<<<dim3(NB * 12), dim3(256), 0, stream>>>(Q, qs, Kp, ks2, Vp, vs, O, D, Tq, Tk);
    };

    // pre-norm transformer block. Xin: residual input (read-only view for LN1 + first
    // residual-add); Xf/Xb: fp32 residual stream + bf16 mirror (written from first
    // residual-add onward). Xin==Xf except encoder layer 0 (Xin=ctx, saves the memcpy).
    auto tblock = [&](const float* Xin, float* Xf, u16* Xb, int Mtok, int Tseq, int basei,
                      int l, const u16* Wqkv, const u16* Wo, const u16* W1, const u16* W2) {
        const float* ln1g = IN(basei + 0) + l * D;
        const float* ln1b = IN(basei + 1) + l * D;
        const float* bqkv = IN(basei + 3) + l * 3 * D;
        const float* bo = IN(basei + 5) + l * D;
        const float* ln2g = IN(basei + 6) + l * D;
        const float* ln2b = IN(basei + 7) + l * D;
        const float* b1 = IN(basei + 9) + l * FF;
        const float* b2 = IN(basei + 11) + l * D;

        ln(Xin, ln1g, ln1b, hb, nullptr, Mtok);
        gemm(0, hb, Wqkv, bqkv, nullptr, nullptr, s1b, Mtok, 3 * D, D);         // qkv -> bf16
        attn(s1b, 3 * D, s1b + D, 3 * D, s1b + 2 * D, 3 * D, hb, Tseq, Tseq);   // self-attn -> hb
        gemm(1, hb, Wo, bo, Xin, Xf, Xb, Mtok, D, D);                           // Xf = Xin + ao@wo+bo
        ln(Xf, ln2g, ln2b, hb, nullptr, Mtok);
        gemm(2, hb, W1, b1, nullptr, nullptr, s1b, Mtok, FF, D);                // gelu -> bf16
        gemm(1, s1b, W2, b2, Xf, Xf, Xb, Mtok, D, FF);                          // x += ff@w2+b2
    };

    // ---------------- encoder (layer 0 reads ctx directly; no memcpy) ----------------
    for (int l = 0; l < NL; ++l)
        tblock((l == 0) ? IN(0) : x, x, xb, Menc, S, 5, l,
               encWqkv + (long long)l * D * 3 * D, encWo + (long long)l * D * D,
               encW1 + (long long)l * D * FF, encW2 + (long long)l * FF * D);

    // ---------------- decoder ----------------
    k_gatherB<<<dim3(Mdec), dim3(256), 0, stream>>>(spe, tpos, flagD, qb);
    u16* qq = s1b;                                       // [Mdec, D]
    u16* kkvv = s1b + (long long)Mdec * D;               // [Menc, 1536] (kk | vv)
    for (int l = 0; l < NL; ++l) {
        gemm(0, qb, caWq + (long long)l * D * D, IN(30) + l * D, nullptr, nullptr, qq, Mdec, D, D);
        gemm(0, xb, caWkv + (long long)l * 2 * D * D, bkv[l], nullptr, nullptr, kkvv, Menc, 2 * D, D);
        attn(qq, D, kkvv, 2 * D, kkvv + D, 2 * D, hb, T, S);                    // cross-attn
        gemm(3, hb, caWo + (long long)l * D * D, IN(36) + l * D, nullptr, q, qb, Mdec, D, D);
        tblock(q, q, qb, Mdec, T, 17, l,
               decWqkv + (long long)l * D * 3 * D, decWo + (long long)l * D * D,
               decW1 + (long long)l * D * FF, decW2 + (long long)l * FF * D);
    }
    ln(q, norm_g, norm_b, nullptr, (float*)d_out, Mdec);
}

// Round 22
// 2556.402 us; speedup vs baseline: 1.2192x; 1.1326x over previous
//
#include <hip/hip_runtime.h>

typedef unsigned short u16;
typedef __attribute__((ext_vector_type(8))) __bf16 bf16x8;
typedef __attribute__((ext_vector_type(4))) float f32x4;

#define DEV static __device__ __forceinline__

#define ARENA_BYTES 349700096ULL
__device__ __align__(256) char g_arena[ARENA_BYTES];

DEV float bf2f(u16 u) { return __uint_as_float(((unsigned)u) << 16); }
DEV u16 f2bf(float f) {
    unsigned u = __float_as_uint(f);
    return (u16)((u + 0x7fffu + ((u >> 16) & 1u)) >> 16);
}
// tanh-GELU via sigmoid identity + hw exp (proven r17)
DEV float gelu_fast(float x) {
    float x3 = x * x * x;
    float u = 1.5957691216057308f * x + 0.0713548162726009f * x3;
    return x / (1.f + __expf(-u));
}

// ---- async global->LDS, 16B per lane (m97 pattern; lane i -> ldsbase + i*16) ----
DEV void gload16(const u16* gp, u16* lp) {
    __builtin_amdgcn_global_load_lds((const __attribute__((address_space(1))) void*)gp,
                                     (__attribute__((address_space(3))) void*)lp, 16, 0, 0);
}

// ---- target_positions dtype sniff ----
__global__ __launch_bounds__(256) void k_detect_i64(const int* __restrict__ pos, int nhalf,
                                                    int* __restrict__ flagD) {
    int i = blockIdx.x * 256 + threadIdx.x;
    if (i < nhalf && pos[2 * i + 1] != 0) atomicAnd(flagD, 0);
}

// ---- gather rows of spatial_pos_embed -> bf16 (vectorized: 8 elems/thread) ----
__global__ __launch_bounds__(256) void k_gatherB(const float* __restrict__ spe,
                                                 const int* __restrict__ pos,
                                                 const int* __restrict__ flagD,
                                                 u16* __restrict__ qb) {
    int row = blockIdx.x;
    int p = (*flagD) ? pos[2 * row] : pos[row];
    p = (p < 0) ? 0 : (p > 195 ? 195 : p);
    const float* src = spe + (size_t)p * 768;
    u16* dst = qb + (size_t)row * 768;
    int j = threadIdx.x;               // 96 chunks of 8
    if (j < 96) {
        float4 a = *(const float4*)&src[j * 8];
        float4 b = *(const float4*)&src[j * 8 + 4];
        union { u16 u[8]; int4 v; } t;
        t.u[0] = f2bf(a.x); t.u[1] = f2bf(a.y); t.u[2] = f2bf(a.z); t.u[3] = f2bf(a.w);
        t.u[4] = f2bf(b.x); t.u[5] = f2bf(b.y); t.u[6] = f2bf(b.z); t.u[7] = f2bf(b.w);
        *(int4*)&dst[j * 8] = t.v;
    }
}

// ---- LayerNorm over 768: fp32 in, bf16 out (OUTF32=0) or fp32 out (final) ----
template <int OUTF32>
__global__ __launch_bounds__(256) void k_ln(const float* __restrict__ X,
                                            const float* __restrict__ g,
                                            const float* __restrict__ b,
                                            u16* __restrict__ Ob, float* __restrict__ Of) {
    const int row = blockIdx.x, tid = threadIdx.x;
    const float* xr = X + (size_t)row * 768;
    float v0 = xr[tid], v1 = xr[tid + 256], v2 = xr[tid + 512];
    float s = v0 + v1 + v2, s2 = v0 * v0 + v1 * v1 + v2 * v2;
#pragma unroll
    for (int off = 32; off; off >>= 1) {
        s += __shfl_xor(s, off);
        s2 += __shfl_xor(s2, off);
    }
    __shared__ float red[8];
    const int wid = tid >> 6, lane = tid & 63;
    if (lane == 0) { red[wid] = s; red[4 + wid] = s2; }
    __syncthreads();
    s = red[0] + red[1] + red[2] + red[3];
    s2 = red[4] + red[5] + red[6] + red[7];
    const float mu = s * (1.f / 768.f);
    const float var = fmaxf(s2 * (1.f / 768.f) - mu * mu, 0.f);
    const float rs = rsqrtf(var + 1e-5f);
    size_t o = (size_t)row * 768;
#pragma unroll
    for (int i = 0; i < 3; ++i) {
        int c = tid + 256 * i;
        float vv = (i == 0 ? v0 : (i == 1 ? v1 : v2));
        float y = (vv - mu) * rs * g[c] + b[c];
        if (OUTF32) Of[o + c] = y;
        else        Ob[o + c] = f2bf(y);
    }
}

// ---- batched weight transpose+convert: L layers, W[l][K,N] -> WT[l][N,K] ----
__global__ __launch_bounds__(256) void k_wtransL(const float* __restrict__ W,
                                                 u16* __restrict__ WT, int K, int N,
                                                 long long srcLs, long long dstLs,
                                                 long long per, int L) {
    long long idx = (long long)blockIdx.x * 256 + threadIdx.x;
    if (idx >= per * L) return;
    int l = (int)(idx / per);
    long long r = idx % per;
    int n = (int)(r % N);
    int kc = (int)(r / N);
    const float* Wl = W + (long long)l * srcLs;
    u16* WTl = WT + (long long)l * dstLs;
    union { u16 u[8]; int4 v; } tmp;
#pragma unroll
    for (int j = 0; j < 8; ++j) tmp.u[j] = f2bf(Wl[(size_t)(kc * 8 + j) * N + n]);
    *(int4*)&WTl[(size_t)n * K + kc * 8] = tmp.v;
}

// ---- bf16 MFMA GEMM (r17-proven): 128x128 tile, BK=64, double-buffered 2-phase
//      prefetch, XOR-swizzled gload_lds staging, bijective XCD block swizzle. ----
template <bool GELU_, bool RES_, bool OF32, bool OBF>
__global__ __launch_bounds__(256) void k_gemmB(const u16* __restrict__ A,
                                               const u16* __restrict__ BT,
                                               const float* __restrict__ bias,
                                               const float* __restrict__ R,
                                               float* __restrict__ Cf, u16* __restrict__ Cb,
                                               int M, int N, int K) {
    __shared__ __align__(16) u16 Asm[2][128 * 64];
    __shared__ __align__(16) u16 Bsm[2][128 * 64];
    const int tid = threadIdx.x;
    const int lane = tid & 63;
    const int wid = tid >> 6;
    const int wm = wid >> 1, wn = wid & 1;

    // XCD-chunked bijective swizzle; N-tile-fastest within a chunk (A-panel L2 reuse)
    const int nbx = gridDim.x, nby = gridDim.y;
    const int nwg = nbx * nby;
    const int bid = blockIdx.y * nbx + blockIdx.x;
    const int q8 = nwg >> 3, r8 = nwg & 7;
    const int xcd = bid & 7, pos = bid >> 3;
    const int swz = (xcd < r8 ? xcd * (q8 + 1) : r8 * (q8 + 1) + (xcd - r8) * q8) + pos;
    const int tyy = swz % nby;     // N-tile
    const int txx = swz / nby;     // M-tile

    // staging: lane covers row (lane>>3) in its 8-row group, phys granule (lane&7);
    // global (logical) granule = (lane&7) ^ (lane>>3)  [XOR swizzle, bit-exact r14]
    const int srow = lane >> 3;
    const int sgr = (lane & 7) ^ srow;
    const int fr = lane & 15, g = lane >> 4;
    const int s7 = fr & 7;          // read-side swizzle selector (= row & 7)

    const u16* Ab = A + (size_t)txx * 128 * K + (size_t)srow * K + sgr * 8;
    const u16* Bb = BT + (size_t)tyy * 128 * K + (size_t)srow * K + sgr * 8;

    f32x4 acc[4][4] = {};
    const int nIter = K >> 6;

    // prologue: stage tile 0 into buffer 0
#pragma unroll
    for (int n = 0; n < 4; ++n) {
        const int rg = wid * 32 + n * 8;
        gload16(Ab + (size_t)rg * K, &Asm[0][rg * 64]);
        gload16(Bb + (size_t)rg * K, &Bsm[0][rg * 64]);
    }
    __syncthreads();

    int cur = 0;
    for (int t = 0; t < nIter; ++t) {
        if (t + 1 < nIter) {
            const int k0 = (t + 1) << 6;
#pragma unroll
            for (int n = 0; n < 4; ++n) {
                const int rg = wid * 32 + n * 8;
                gload16(Ab + (size_t)rg * K + k0, &Asm[cur ^ 1][rg * 64]);
                gload16(Bb + (size_t)rg * K + k0, &Bsm[cur ^ 1][rg * 64]);
            }
        }
        const u16* As = &Asm[cur][0];
        const u16* Bs = &Bsm[cur][0];
#pragma unroll
        for (int kk = 0; kk < 2; ++kk) {
            const int gr8 = (((kk * 4 + g) ^ s7) << 3);
            bf16x8 af[4], bfr[4];
#pragma unroll
            for (int i = 0; i < 4; ++i)
                af[i] = *(const bf16x8*)&As[(wm * 64 + i * 16 + fr) * 64 + gr8];
#pragma unroll
            for (int j = 0; j < 4; ++j)
                bfr[j] = *(const bf16x8*)&Bs[(wn * 64 + j * 16 + fr) * 64 + gr8];
#pragma unroll
            for (int i = 0; i < 4; ++i)
#pragma unroll
                for (int j = 0; j < 4; ++j)
                    acc[i][j] = __builtin_amdgcn_mfma_f32_16x16x32_bf16(af[i], bfr[j], acc[i][j], 0, 0, 0);
        }
        __syncthreads();
        cur ^= 1;
    }

    // C/D layout: col=lane&15, row=(lane>>4)*4+reg  [HW-verified m89/m91]
    const int g4 = (lane >> 4) * 4;
#pragma unroll
    for (int j = 0; j < 4; ++j) {
        const int col = tyy * 128 + wn * 64 + j * 16 + fr;
        const float bc = bias[col];
#pragma unroll
        for (int i = 0; i < 4; ++i) {
#pragma unroll
            for (int r = 0; r < 4; ++r) {
                const int row = txx * 128 + wm * 64 + i * 16 + g4 + r;
                float v = acc[i][j][r] + bc;
                if (GELU_) v = gelu_fast(v);
                if (RES_)  v += R[(size_t)row * N + col];
                if (OF32)  Cf[(size_t)row * N + col] = v;
                if (OBF)   Cb[(size_t)row * N + col] = f2bf(v);
            }
        }
    }
}

// ---- MFMA flash attention, bf16 in/out (r11-r21 structure; staging vectorized) ----
__global__ __launch_bounds__(256) void k_attnM(const u16* __restrict__ Qp, int qs,
                                               const u16* __restrict__ Kp, int ks,
                                               const u16* __restrict__ Vp, int vs,
                                               u16* __restrict__ Op, int os,
                                               int Tq, int Tk) {
    __shared__ u16 kl[208][72];
    __shared__ u16 vt[64][272];
    __shared__ u16 pl[4][16][72];
    const int bh = blockIdx.x, b = bh / 12, h = bh % 12;
    const int tid = threadIdx.x, lane = tid & 63, wid = tid >> 6;
    const int fr = lane & 15, g = lane >> 4, g4 = g * 4;

    const int Tkp = (Tk + 15) & ~15;
    const int NC = (Tkp + 63) >> 6;
    const int TC = NC << 6;

    // K staging: 16B chunks (8 bf16); rows ks-strided are 16B-aligned for ks in {768,1536,2304}
    const int4 zero4 = {0, 0, 0, 0};
    for (int c = tid; c < Tkp * 8; c += 256) {
        int r = c >> 3, j = c & 7;
        int4 v = (r < Tk) ? *(const int4*)&Kp[((size_t)b * Tk + r) * ks + h * 64 + j * 8]
                          : zero4;
        *(int4*)&kl[r][j * 8] = v;
    }
    // V staging (transposed): vector global read, 8 scalar LDS scatter-writes
    for (int c = tid; c < TC * 8; c += 256) {
        int t = c >> 3, j = c & 7;
        union { u16 u[8]; int4 v; } w;
        w.v = (t < Tk) ? *(const int4*)&Vp[((size_t)b * Tk + t) * vs + h * 64 + j * 8]
                       : zero4;
#pragma unroll
        for (int i = 0; i < 8; ++i) vt[j * 8 + i][t] = w.u[i];
    }
    __syncthreads();

    const int NT = (Tq + 63) >> 6;
    for (int it = 0; it < NT; ++it) {
        const int qb = (it << 6) + (wid << 4);
        if (qb >= Tq) continue;

        int qr = qb + fr;
        if (qr >= Tq) qr = 0;
        const u16* Qrow = Qp + ((size_t)b * Tq + qr) * qs + h * 64;
        bf16x8 afq0 = *(const bf16x8*)&Qrow[g * 8];
        bf16x8 afq1 = *(const bf16x8*)&Qrow[32 + g * 8];

        f32x4 acc_o[4] = {};
        float m_r[4] = {-1e30f, -1e30f, -1e30f, -1e30f};
        float lp[4] = {0.f, 0.f, 0.f, 0.f};

        for (int c = 0; c < NC; ++c) {
            const int tk0 = c << 6;
            int NF = (Tkp - tk0) >> 4;
            if (NF > 4) NF = 4;

            f32x4 acc_s[4] = {};
#pragma unroll
            for (int nf = 0; nf < 4; ++nf) {
                if (nf < NF) {
                    const u16* kr = &kl[tk0 + nf * 16 + fr][0];
                    acc_s[nf] = __builtin_amdgcn_mfma_f32_16x16x32_bf16(
                        afq0, *(const bf16x8*)&kr[g * 8], acc_s[nf], 0, 0, 0);
                    acc_s[nf] = __builtin_amdgcn_mfma_f32_16x16x32_bf16(
                        afq1, *(const bf16x8*)&kr[32 + g * 8], acc_s[nf], 0, 0, 0);
                }
            }
            float pm[4] = {-1e30f, -1e30f, -1e30f, -1e30f};
#pragma unroll
            for (int nf = 0; nf < 4; ++nf) {
                if (nf < NF) {
                    const bool cv = (tk0 + nf * 16 + fr) < Tk;
#pragma unroll
                    for (int r = 0; r < 4; ++r) {
                        float sv = acc_s[nf][r] * 0.125f;
                        acc_s[nf][r] = sv;
                        if (cv) pm[r] = fmaxf(pm[r], sv);
                    }
                }
            }
#pragma unroll
            for (int off = 1; off < 16; off <<= 1)
#pragma unroll
                for (int r = 0; r < 4; ++r) pm[r] = fmaxf(pm[r], __shfl_xor(pm[r], off));
            float al[4];
#pragma unroll
            for (int r = 0; r < 4; ++r) {
                float mn = fmaxf(m_r[r], pm[r]);
                al[r] = __expf(m_r[r] - mn);
                m_r[r] = mn;
                lp[r] *= al[r];
            }
#pragma unroll
            for (int nfd = 0; nfd < 4; ++nfd)
#pragma unroll
                for (int r = 0; r < 4; ++r) acc_o[nfd][r] *= al[r];
#pragma unroll
            for (int nf = 0; nf < 4; ++nf) {
                const bool cv = (nf < NF) && ((tk0 + nf * 16 + fr) < Tk);
#pragma unroll
                for (int r = 0; r < 4; ++r) {
                    float w = cv ? __expf(acc_s[nf][r] - m_r[r]) : 0.f;
                    lp[r] += w;
                    pl[wid][g4 + r][nf * 16 + fr] = f2bf(w);
                }
            }
#pragma unroll
            for (int ksp = 0; ksp < 2; ++ksp) {
                bf16x8 ap = *(const bf16x8*)&pl[wid][fr][ksp * 32 + g * 8];
#pragma unroll
                for (int nfd = 0; nfd < 4; ++nfd)
                    acc_o[nfd] = __builtin_amdgcn_mfma_f32_16x16x32_bf16(
                        ap, *(const bf16x8*)&vt[nfd * 16 + fr][tk0 + ksp * 32 + g * 8],
                        acc_o[nfd], 0, 0, 0);
            }
        }
#pragma unroll
        for (int off = 1; off < 16; off <<= 1)
#pragma unroll
            for (int r = 0; r < 4; ++r) lp[r] += __shfl_xor(lp[r], off);
#pragma unroll
        for (int r = 0; r < 4; ++r) {
            int qrow = qb + g4 + r;
            if (qrow < Tq) {
                float inv = 1.f / lp[r];
#pragma unroll
                for (int nfd = 0; nfd < 4; ++nfd)
                    Op[((size_t)b * Tq + qrow) * os + h * 64 + nfd * 16 + fr] =
                        f2bf(acc_o[nfd][r] * inv);
            }
        }
    }
}

// =======================================================================================
extern "C" void kernel_launch(void* const* d_in, const int* in_sizes, int n_in,
                              void* d_out, int out_size, void* d_ws, size_t ws_size,
                              hipStream_t stream) {
    const int D = 768, FF = 3072, NB = 64, S = 196, T = 98, NL = 3;
    const int Menc = NB * S;   // 12544
    const int Mdec = NB * T;   // 6272

    auto IN = [&](int i) { return (const float*)d_in[i]; };
    const int* tpos = (const int*)d_in[1];
    const float* spe = IN(2);
    const float* norm_g = IN(3);
    const float* norm_b = IN(4);

    char* base;
    if (ws_size >= ARENA_BYTES) {
        base = (char*)d_ws;
    } else {
        void* sym = nullptr;
        if (hipGetSymbolAddress(&sym, HIP_SYMBOL(g_arena)) == hipSuccess && sym)
            base = (char*)sym;
        else
            base = (char*)d_ws;
    }
    char* pp = base;
    auto alloc = [&](long long bytes) -> void* {
        void* r = (void*)pp;
        pp += (bytes + 255) & ~255LL;
        return r;
    };
    int* flag = (int*)alloc(256);
    int* flagD = flag + 1;

    // ---- batched weight pre-conversion: W[L][K,N] fp32 -> WT[L][N,K] bf16 ----
    auto cvb = [&](const float* W, int K, int N, int L, long long dstLs, u16* dst) {
        long long per = (long long)N * (K / 8);
        long long tot = per * L;
        k_wtransL<<<dim3((int)((tot + 255) / 256)), dim3(256), 0, stream>>>(
            W, dst, K, N, (long long)K * N, dstLs, per, L);
    };
    auto cva = [&](const float* W, int K, int N, int L) -> u16* {
        u16* dst = (u16*)alloc((long long)L * K * N * 2);
        cvb(W, K, N, L, (long long)K * N, dst);
        return dst;
    };
    u16* encWqkv = cva(IN(7), D, 3 * D, 3);
    u16* encWo = cva(IN(9), D, D, 3);
    u16* encW1 = cva(IN(13), D, FF, 3);
    u16* encW2 = cva(IN(15), FF, D, 3);
    u16* decWqkv = cva(IN(19), D, 3 * D, 3);
    u16* decWo = cva(IN(21), D, D, 3);
    u16* decW1 = cva(IN(25), D, FF, 3);
    u16* decW2 = cva(IN(27), FF, D, 3);
    u16* caWq = cva(IN(29), D, D, 3);
    u16* caWkv = (u16*)alloc((long long)3 * 2 * D * D * 2);   // [l][wk rows | wv rows][768]
    cvb(IN(31), D, D, 3, (long long)2 * D * D, caWkv);
    cvb(IN(33), D, D, 3, (long long)2 * D * D, caWkv + (long long)D * D);
    u16* caWo = cva(IN(35), D, D, 3);
    float* bkv[3];
    for (int l = 0; l < NL; ++l) {
        bkv[l] = (float*)alloc(2 * D * 4);
        hipMemcpyAsync(bkv[l], IN(32) + l * D, D * 4, hipMemcpyDeviceToDevice, stream);
        hipMemcpyAsync(bkv[l] + D, IN(34) + l * D, D * 4, hipMemcpyDeviceToDevice, stream);
    }

    float* x = (float*)alloc((long long)Menc * D * 4);   // fp32 residual (enc)
    float* q = (float*)alloc((long long)Mdec * D * 4);   // fp32 residual (dec)
    u16* xb = (u16*)alloc((long long)Menc * D * 2);      // bf16 mirror of x
    u16* qb = (u16*)alloc((long long)Mdec * D * 2);      // bf16 mirror of q
    u16* hb = (u16*)alloc((long long)Menc * D * 2);      // bf16 LN/attn out
    u16* s1b = (u16*)alloc((long long)Menc * FF * 2);    // bf16 qkv / ff1 / dec qq,kkvv

    hipMemsetAsync(flagD, 0x01, 4, stream);
    k_detect_i64<<<dim3((Mdec / 2 + 255) / 256), dim3(256), 0, stream>>>(tpos, Mdec / 2, flagD);

    // modes: 0 plain->bf16 | 1 res->fp32+bf16 | 2 gelu->bf16 | 3 plain->fp32+bf16
    auto gemm = [&](int mode, const u16* A, const u16* WT, const float* bias,
                    const float* R, float* Cf, u16* Cb, int M, int N, int K) {
        dim3 g(M / 128, N / 128), blk(256);
        switch (mode) {
            case 0: k_gemmB<false, false, false, true><<<g, blk, 0, stream>>>(A, WT, bias, nullptr, nullptr, Cb, M, N, K); break;
            case 1: k_gemmB<false, true, true, true><<<g, blk, 0, stream>>>(A, WT, bias, R, Cf, Cb, M, N, K); break;
            case 2: k_gemmB<true, false, false, true><<<g, blk, 0, stream>>>(A, WT, bias, nullptr, nullptr, Cb, M, N, K); break;
            case 3: k_gemmB<false, false, true, true><<<g, blk, 0, stream>>>(A, WT, bias, nullptr, Cf, Cb, M, N, K); break;
        }
    };
    auto ln = [&](const float* X, const float* gg, const float* bb, u16* Ob, float* Of, int M) {
        if (Ob) k_ln<0><<<dim3(M), dim3(256), 0, stream>>>(X, gg, bb, Ob, nullptr);
        else    k_ln<1><<<dim3(M), dim3(256), 0, stream>>>(X, gg, bb, nullptr, Of);
    };
    auto attn = [&](const u16* Q, int qs, const u16* Kp, int ks2, const u16* Vp, int vs,
                    u16* O, int Tq, int Tk) {
        k_attnM<<<dim3(NB * 12), dim3(256), 0, stream>>>(Q, qs, Kp, ks2, Vp, vs, O, D, Tq, Tk);
    };

    // pre-norm transformer block. Xin: residual input (read-only view for LN1 + first
    // residual-add); Xf/Xb: fp32 residual stream + bf16 mirror. Xin==Xf except enc L0.
    auto tblock = [&](const float* Xin, float* Xf, u16* Xb, int Mtok, int Tseq, int basei,
                      int l, const u16* Wqkv, const u16* Wo, const u16* W1, const u16* W2) {
        const float* ln1g = IN(basei + 0) + l * D;
        const float* ln1b = IN(basei + 1) + l * D;
        const float* bqkv = IN(basei + 3) + l * 3 * D;
        const float* bo = IN(basei + 5) + l * D;
        const float* ln2g = IN(basei + 6) + l * D;
        const float* ln2b = IN(basei + 7) + l * D;
        const float* b1 = IN(basei + 9) + l * FF;
        const float* b2 = IN(basei + 11) + l * D;

        ln(Xin, ln1g, ln1b, hb, nullptr, Mtok);
        gemm(0, hb, Wqkv, bqkv, nullptr, nullptr, s1b, Mtok, 3 * D, D);         // qkv -> bf16
        attn(s1b, 3 * D, s1b + D, 3 * D, s1b + 2 * D, 3 * D, hb, Tseq, Tseq);   // self-attn -> hb
        gemm(1, hb, Wo, bo, Xin, Xf, Xb, Mtok, D, D);                           // Xf = Xin + ao@wo+bo
        ln(Xf, ln2g, ln2b, hb, nullptr, Mtok);
        gemm(2, hb, W1, b1, nullptr, nullptr, s1b, Mtok, FF, D);                // gelu -> bf16
        gemm(1, s1b, W2, b2, Xf, Xf, Xb, Mtok, D, FF);                          // x += ff@w2+b2
    };

    // ---------------- encoder (layer 0 reads ctx directly; no memcpy) ----------------
    for (int l = 0; l < NL; ++l)
        tblock((l == 0) ? IN(0) : x, x, xb, Menc, S, 5, l,
               encWqkv + (long long)l * D * 3 * D, encWo + (long long)l * D * D,
               encW1 + (long long)l * D * FF, encW2 + (long long)l * FF * D);

    // ---------------- decoder ----------------
    k_gatherB<<<dim3(Mdec), dim3(256), 0, stream>>>(spe, tpos, flagD, qb);
    u16* qq = s1b;                                       // [Mdec, D]
    u16* kkvv = s1b + (long long)Mdec * D;               // [Menc, 1536] (kk | vv)
    for (int l = 0; l < NL; ++l) {
        gemm(0, qb, caWq + (long long)l * D * D, IN(30) + l * D, nullptr, nullptr, qq, Mdec, D, D);
        gemm(0, xb, caWkv + (long long)l * 2 * D * D, bkv[l], nullptr, nullptr, kkvv, Menc, 2 * D, D);
        attn(qq, D, kkvv, 2 * D, kkvv + D, 2 * D, hb, T, S);                    // cross-attn
        gemm(3, hb, caWo + (long long)l * D * D, IN(36) + l * D, nullptr, q, qb, Mdec, D, D);
        tblock(q, q, qb, Mdec, T, 17, l,
               decWqkv + (long long)l * D * 3 * D, decWo + (long long)l * D * D,
               decW1 + (long long)l * D * FF, decW2 + (long long)l * FF * D);
    }
    ln(q, norm_g, norm_b, nullptr, (float*)d_out, Mdec);
}